// Round 2
// baseline (1935.858 us; speedup 1.0000x reference)
//
#include <hip/hip_runtime.h>
#include <math.h>

#define NB 4
#define NV 8
#define NC 32
#define NG 65536
#define IMGW 256

static constexpr long long STACKED_ELEMS = (long long)NB * NV * NG * NC; // 67108864

// ---------------- adjacency: A (to d_out tail) and A_tilde (to ws) ----------------
__global__ __launch_bounds__(256) void adj_kernel(const float* __restrict__ ext,
                                                  float* __restrict__ A_out,
                                                  float* __restrict__ At_out)
{
    __shared__ float ctr[NB * NV][3];
    __shared__ float Dsh[NB * NV * NV];
    int t = threadIdx.x;
    if (t < NB * NV) {
        const float* E = ext + t * 16;
        #pragma unroll
        for (int i = 0; i < 3; i++) {
            // centers_i = -sum_j R[j][i] * t[j];  R[j][i]=E[j*4+i], t[j]=E[j*4+3]
            float s = E[0 * 4 + i] * E[0 * 4 + 3]
                    + E[1 * 4 + i] * E[1 * 4 + 3]
                    + E[2 * 4 + i] * E[2 * 4 + 3];
            ctr[t][i] = -s;
        }
    }
    __syncthreads();
    {
        int b = t >> 6, i = (t >> 3) & 7, j = t & 7;
        float dx = ctr[b * 8 + i][0] - ctr[b * 8 + j][0];
        float dy = ctr[b * 8 + i][1] - ctr[b * 8 + j][1];
        float dz = ctr[b * 8 + i][2] - ctr[b * 8 + j][2];
        Dsh[t] = dx * dx + dy * dy + dz * dz;
    }
    __syncthreads();
    if (t < NB * NV) {
        int ri = t & 7;
        const float* drow = &Dsh[t * 8];
        bool chosen[8] = {false, false, false, false, false, false, false, false};
        // top-3 of sim = -dist_sq, diag excluded; ties -> lowest index (strict >)
        for (int n = 0; n < 3; n++) {
            int best = -1; float bs = -3.0e38f;
            for (int j2 = 0; j2 < 8; j2++) {
                if (j2 == ri || chosen[j2]) continue;
                float s = -drow[j2];
                if (s > bs) { bs = s; best = j2; }
            }
            chosen[best] = true;
        }
        float row[8]; float deg = 0.f;
        #pragma unroll
        for (int j2 = 0; j2 < 8; j2++) {
            float a = 0.f;
            if (j2 == ri)        a = 1.0f;
            else if (chosen[j2]) a = 1.0f / (1.0f + sqrtf(drow[j2] + 1e-6f));
            row[j2] = a; deg += a;
        }
        float dn = deg + (deg == 0.f ? 1.f : 0.f);
        #pragma unroll
        for (int j2 = 0; j2 < 8; j2++) {
            A_out[t * 8 + j2]  = row[j2];
            At_out[t * 8 + j2] = row[j2] / dn;
        }
    }
}

// ---------------- fused linear + weighted scatter-add ----------------
// One 32-lane group per source row (b,j,g); lane c owns output channel c.
__global__ __launch_bounds__(256) void scatter_kernel(
    const float*  __restrict__ features, // (B,V,G,C)
    const float2* __restrict__ xy,       // (B,V,V,G) of float2
    const float*  __restrict__ Wlin,     // (C_in, C_out) row-major
    const float*  __restrict__ blin,     // (C_out)
    const float*  __restrict__ Atld,     // (B,V,V)
    float*        __restrict__ grid,     // (ni, B, G, C)
    int i0, int ni)
{
    __shared__ float At_s[NB * NV * NV];
    __shared__ __align__(16) float rowbuf[8][NC];
    int t = threadIdx.x;
    int c = t & 31;
    int grp = t >> 5;
    At_s[t] = Atld[t];
    float bias = blin[c];
    float wcol[NC];
    #pragma unroll
    for (int k = 0; k < NC; k++) wcol[k] = Wlin[k * NC + c];

    const long long totalBatches = (long long)NB * NV * NG / 8; // 262144
    for (long long batch = blockIdx.x; batch < totalBatches; batch += gridDim.x) {
        long long row = batch * 8 + grp;
        __syncthreads();
        rowbuf[grp][c] = features[row * NC + c];
        __syncthreads();
        float acc = bias;
        const float4* rb4 = (const float4*)rowbuf[grp];
        #pragma unroll
        for (int kk = 0; kk < 8; kk++) {
            float4 f4 = rb4[kk];
            acc = fmaf(f4.x, wcol[4 * kk + 0], acc);
            acc = fmaf(f4.y, wcol[4 * kk + 1], acc);
            acc = fmaf(f4.z, wcol[4 * kk + 2], acc);
            acc = fmaf(f4.w, wcol[4 * kk + 3], acc);
        }
        int g = (int)(row & (NG - 1));
        int j = (int)((row >> 16) & 7);
        int b = (int)(row >> 19);
        const float2* xyrow = xy + ((long long)(b * 8 + j) * 8) * NG + g;
        for (int ii = 0; ii < ni; ii++) {
            int i = i0 + ii;
            float2 p = xyrow[(long long)i * NG];
            float px = fminf(fmaxf(rintf(p.x), 0.f), (float)(IMGW - 1));
            float py = fminf(fmaxf(rintf(p.y), 0.f), (float)(IMGW - 1));
            int pix = (int)py * IMGW + (int)px;
            float w = At_s[(b * NV + i) * NV + j];
            unsafeAtomicAdd(&grid[(((long long)ii * NB + b) * NG + pix) * NC + c], acc * w);
        }
    }
}

// ---------------- gather: out[b,i,g,:] = grid[ii][b][idx(b,i,i,g)][:] ----------------
__global__ __launch_bounds__(256) void gather_kernel(
    const float2* __restrict__ xy,
    const float*  __restrict__ grid,
    float*        __restrict__ out,
    int i0, int ni)
{
    long long id = (long long)blockIdx.x * blockDim.x + threadIdx.x;
    long long total = (long long)ni * NB * NG * NC;
    if (id >= total) return;
    int c = (int)(id & 31);
    long long r = id >> 5;
    int g = (int)(r & (NG - 1));
    long long r2 = r >> 16;
    int b = (int)(r2 & (NB - 1));
    int ii = (int)(r2 >> 2);
    int i = i0 + ii;
    float2 p = xy[((long long)((b * NV + i) * NV + i)) * NG + g];
    float px = fminf(fmaxf(rintf(p.x), 0.f), (float)(IMGW - 1));
    float py = fminf(fmaxf(rintf(p.y), 0.f), (float)(IMGW - 1));
    int pix = (int)py * IMGW + (int)px;
    out[(((long long)(b * NV + i) * NG) + g) * NC + c] =
        grid[(((long long)ii * NB + b) * NG + pix) * NC + c];
}

extern "C" void kernel_launch(void* const* d_in, const int* in_sizes, int n_in,
                              void* d_out, int out_size, void* d_ws, size_t ws_size,
                              hipStream_t stream)
{
    const float*  features = (const float*)d_in[0];
    const float*  xy       = (const float*)d_in[1];
    const float*  ext      = (const float*)d_in[2];
    const float*  Wlin     = (const float*)d_in[3];
    const float*  blin     = (const float*)d_in[4];
    float* out = (float*)d_out;

    const size_t gridOne = (size_t)NB * NG * NC * sizeof(float); // 33,554,432 B per view
    size_t avail = ws_size > 4096 ? ws_size - 4096 : 0;
    int chunk = (int)(avail / gridOne);
    if (chunk > NV) chunk = NV;
    if (chunk < 1) chunk = 1; // assume ws can hold at least one view's grid
    float* grid = (float*)d_ws;
    float* At   = (float*)((char*)d_ws + (size_t)chunk * gridOne);

    adj_kernel<<<1, 256, 0, stream>>>(ext, out + STACKED_ELEMS, At);

    for (int i0 = 0; i0 < NV; i0 += chunk) {
        int ni = (NV - i0 < chunk) ? (NV - i0) : chunk;
        hipMemsetAsync(grid, 0, (size_t)ni * gridOne, stream);
        scatter_kernel<<<8192, 256, 0, stream>>>(features, (const float2*)xy,
                                                 Wlin, blin, At, grid, i0, ni);
        long long total = (long long)ni * NB * NG * NC;
        int blocks = (int)((total + 255) / 256);
        gather_kernel<<<blocks, 256, 0, stream>>>((const float2*)xy, grid, out, i0, ni);
    }
}